// Round 1
// baseline (2544.294 us; speedup 1.0000x reference)
//
#include <hip/hip_runtime.h>
#include <hip/hip_bf16.h>

#define N_NODES 100000
#define N_EDGES 3200000
#define FEAT 256
#define HIDDEN 32
#define EMBED 16

// ---------------- degree / norm ----------------

__global__ void k_deg_init(float* __restrict__ deg) {
    int i = blockIdx.x * blockDim.x + threadIdx.x;
    if (i < N_NODES) deg[i] = 1.0f;  // self-loop weight 1
}

__global__ void k_deg_scatter(const int* __restrict__ col,
                              const float* __restrict__ ew,
                              float* __restrict__ deg) {
    int e = blockIdx.x * blockDim.x + threadIdx.x;
    if (e < N_EDGES) unsafeAtomicAdd(&deg[col[e]], ew[e]);
}

__global__ void k_dis(float* __restrict__ deg) {
    int i = blockIdx.x * blockDim.x + threadIdx.x;
    if (i < N_NODES) {
        float d = deg[i];
        deg[i] = (d > 0.0f) ? rsqrtf(d) : 0.0f;  // in-place deg -> deg^{-1/2}
    }
}

__global__ void k_norm(const int* __restrict__ row, const int* __restrict__ col,
                       const float* __restrict__ ew, const float* __restrict__ dis,
                       float* __restrict__ norm) {
    int e = blockIdx.x * blockDim.x + threadIdx.x;
    if (e < N_EDGES) norm[e] = dis[row[e]] * ew[e] * dis[col[e]];
}

// ---------------- layer 1 GEMM: h = x @ W1^T ; out1 = h*dis^2 + b1 ----------------
// 8 threads per row; thread owns 4 consecutive output features.
// x/W reads are 8-lane same-address float4 broadcasts (L1-served); each x row
// is fetched from HBM exactly once. h and out1 writes are fully coalesced float4.

__global__ __launch_bounds__(256) void k_gemm1(
        const float* __restrict__ x, const float* __restrict__ W1,
        const float* __restrict__ b1, const float* __restrict__ dis,
        float* __restrict__ h, float* __restrict__ out1) {
    int t = blockIdx.x * blockDim.x + threadIdx.x;
    int rowi = t >> 3;
    if (rowi >= N_NODES) return;
    int og = t & 7;  // feats og*4 .. og*4+3

    const float4* xr = (const float4*)(x + (size_t)rowi * FEAT);
    const float4* w0 = (const float4*)(W1 + (og * 4 + 0) * FEAT);
    const float4* w1 = (const float4*)(W1 + (og * 4 + 1) * FEAT);
    const float4* w2 = (const float4*)(W1 + (og * 4 + 2) * FEAT);
    const float4* w3 = (const float4*)(W1 + (og * 4 + 3) * FEAT);

    float a0 = 0.f, a1 = 0.f, a2 = 0.f, a3 = 0.f;
#pragma unroll 4
    for (int k = 0; k < FEAT / 4; ++k) {
        float4 xv = xr[k];
        float4 wv;
        wv = w0[k]; a0 += xv.x * wv.x + xv.y * wv.y + xv.z * wv.z + xv.w * wv.w;
        wv = w1[k]; a1 += xv.x * wv.x + xv.y * wv.y + xv.z * wv.z + xv.w * wv.w;
        wv = w2[k]; a2 += xv.x * wv.x + xv.y * wv.y + xv.z * wv.z + xv.w * wv.w;
        wv = w3[k]; a3 += xv.x * wv.x + xv.y * wv.y + xv.z * wv.z + xv.w * wv.w;
    }

    float d = dis[rowi];
    float d2 = d * d;
    float4 bv = *(const float4*)(b1 + og * 4);

    *(float4*)(h + (size_t)rowi * HIDDEN + og * 4) = make_float4(a0, a1, a2, a3);
    *(float4*)(out1 + (size_t)rowi * HIDDEN + og * 4) =
        make_float4(a0 * d2 + bv.x, a1 * d2 + bv.y, a2 * d2 + bv.z, a3 * d2 + bv.w);
}

// ---------------- layer 1 edge scatter: out1[col] += h[row] * norm ----------------
// 8 threads per edge, each handles a float4 of the 32 features.

__global__ void k_scatter1(const int* __restrict__ row, const int* __restrict__ col,
                           const float* __restrict__ norm, const float* __restrict__ h,
                           float* __restrict__ out1) {
    const int total = N_EDGES * 8;
    for (int t = blockIdx.x * blockDim.x + threadIdx.x; t < total;
         t += gridDim.x * blockDim.x) {
        int e = t >> 3;
        int fq = (t & 7) * 4;
        int r = row[e], c = col[e];
        float nv = norm[e];
        float4 hv = *(const float4*)(h + (size_t)r * HIDDEN + fq);
        float* dst = out1 + (size_t)c * HIDDEN + fq;
        unsafeAtomicAdd(dst + 0, hv.x * nv);
        unsafeAtomicAdd(dst + 1, hv.y * nv);
        unsafeAtomicAdd(dst + 2, hv.z * nv);
        unsafeAtomicAdd(dst + 3, hv.w * nv);
    }
}

// ---------------- layer 2 GEMM: h2 = relu(out1) @ W2^T ; out = h2*dis^2 + b2 ----

__global__ void k_gemm2(const float* __restrict__ out1, const float* __restrict__ W2,
                        const float* __restrict__ b2, const float* __restrict__ dis,
                        float* __restrict__ h2, float* __restrict__ out) {
    int t = blockIdx.x * blockDim.x + threadIdx.x;
    int i = t >> 4;
    if (i >= N_NODES) return;
    int f = t & 15;
    const float* r = out1 + (size_t)i * HIDDEN;
    const float* w = W2 + f * HIDDEN;
    float acc = 0.f;
#pragma unroll
    for (int k = 0; k < HIDDEN; ++k) acc += fmaxf(r[k], 0.f) * w[k];
    float d = dis[i];
    h2[(size_t)i * EMBED + f] = acc;
    out[(size_t)i * EMBED + f] = acc * d * d + b2[f];
}

// ---------------- layer 2 edge scatter: out[col] += h2[row] * norm ----------------
// 4 threads per edge, each handles a float4 of the 16 features.

__global__ void k_scatter2(const int* __restrict__ row, const int* __restrict__ col,
                           const float* __restrict__ norm, const float* __restrict__ h2,
                           float* __restrict__ out) {
    const int total = N_EDGES * 4;
    for (int t = blockIdx.x * blockDim.x + threadIdx.x; t < total;
         t += gridDim.x * blockDim.x) {
        int e = t >> 2;
        int fq = (t & 3) * 4;
        int r = row[e], c = col[e];
        float nv = norm[e];
        float4 hv = *(const float4*)(h2 + (size_t)r * EMBED + fq);
        float* dst = out + (size_t)c * EMBED + fq;
        unsafeAtomicAdd(dst + 0, hv.x * nv);
        unsafeAtomicAdd(dst + 1, hv.y * nv);
        unsafeAtomicAdd(dst + 2, hv.z * nv);
        unsafeAtomicAdd(dst + 3, hv.w * nv);
    }
}

extern "C" void kernel_launch(void* const* d_in, const int* in_sizes, int n_in,
                              void* d_out, int out_size, void* d_ws, size_t ws_size,
                              hipStream_t stream) {
    const float* x  = (const float*)d_in[0];
    const int*   ei = (const int*)d_in[1];      // [2, E] int32 (JAX x64 disabled)
    const float* ew = (const float*)d_in[2];
    const float* W1 = (const float*)d_in[3];
    const float* b1 = (const float*)d_in[4];
    const float* W2 = (const float*)d_in[5];
    const float* b2 = (const float*)d_in[6];
    float* out = (float*)d_out;

    const int* row = ei;            // source
    const int* col = ei + N_EDGES;  // target

    // workspace layout (floats): dis[N] | norm[E] | h[N*32] | out1[N*32]
    float* ws   = (float*)d_ws;
    float* dis  = ws;                        // used as deg first, then deg^{-1/2}
    float* norm = dis + N_NODES;
    float* h    = norm + N_EDGES;
    float* out1 = h + (size_t)N_NODES * HIDDEN;
    float* h2   = h;  // alias: h is dead once k_gemm2 runs

    const int B = 256;
    k_deg_init<<<(N_NODES + B - 1) / B, B, 0, stream>>>(dis);
    k_deg_scatter<<<(N_EDGES + B - 1) / B, B, 0, stream>>>(col, ew, dis);
    k_dis<<<(N_NODES + B - 1) / B, B, 0, stream>>>(dis);
    k_norm<<<(N_EDGES + B - 1) / B, B, 0, stream>>>(row, col, ew, dis, norm);
    k_gemm1<<<(N_NODES * 8 + B - 1) / B, B, 0, stream>>>(x, W1, b1, dis, h, out1);
    k_scatter1<<<4096, B, 0, stream>>>(row, col, norm, h, out1);
    k_gemm2<<<(N_NODES * 16 + B - 1) / B, B, 0, stream>>>(out1, W2, b2, dis, h2, out);
    k_scatter2<<<4096, B, 0, stream>>>(row, col, norm, h2, out);
}

// Round 5
// 1005.591 us; speedup vs baseline: 2.5301x; 2.5301x over previous
//
#include <hip/hip_runtime.h>
#include <hip/hip_bf16.h>

#define N_NODES 100000
#define N_EDGES 3200000
#define FEAT 256
#define HIDDEN 32
#define EMBED 16
#define SCAN_B 512
#define NB ((N_NODES + SCAN_B - 1) / SCAN_B)  // 196

// ---------------- init: deg=1 (self loop), cnt=0 ----------------
__global__ void k_init(float* __restrict__ deg, int* __restrict__ cnt) {
    int i = blockIdx.x * blockDim.x + threadIdx.x;
    if (i < N_NODES) { deg[i] = 1.0f; cnt[i] = 0; }
}

// ---------------- per-edge: count targets + weighted degree ----------------
__global__ void k_edge_count(const int* __restrict__ col, const float* __restrict__ ew,
                             int* __restrict__ cnt, float* __restrict__ deg) {
    int e = blockIdx.x * blockDim.x + threadIdx.x;
    if (e < N_EDGES) {
        int c = col[e];
        atomicAdd(&cnt[c], 1);
        unsafeAtomicAdd(&deg[c], ew[e]);
    }
}

__global__ void k_dis(float* __restrict__ deg) {
    int i = blockIdx.x * blockDim.x + threadIdx.x;
    if (i < N_NODES) {
        float d = deg[i];
        deg[i] = (d > 0.0f) ? rsqrtf(d) : 0.0f;  // in-place deg -> deg^{-1/2}
    }
}

// ---------------- exclusive scan of cnt -> off (3 kernels) ----------------
__global__ __launch_bounds__(SCAN_B) void k_scan_block(
        const int* __restrict__ cnt, int* __restrict__ off, int* __restrict__ bsum) {
    __shared__ int s[SCAN_B];
    int tid = threadIdx.x;
    int i = blockIdx.x * SCAN_B + tid;
    int v = (i < N_NODES) ? cnt[i] : 0;
    s[tid] = v;
    __syncthreads();
    for (int d = 1; d < SCAN_B; d <<= 1) {
        int t = (tid >= d) ? s[tid - d] : 0;
        __syncthreads();
        s[tid] += t;
        __syncthreads();
    }
    if (i < N_NODES) off[i] = s[tid] - v;  // exclusive within block
    if (tid == SCAN_B - 1) bsum[blockIdx.x] = s[tid];
}

__global__ void k_scan_bsum(int* __restrict__ bsum) {
    if (threadIdx.x == 0 && blockIdx.x == 0) {
        int run = 0;
        for (int b = 0; b < NB; ++b) { int t = bsum[b]; bsum[b] = run; run += t; }
    }
}

__global__ void k_scan_add(int* __restrict__ off, const int* __restrict__ bsum,
                           int* __restrict__ cur) {
    int i = blockIdx.x * blockDim.x + threadIdx.x;
    if (i < N_NODES) {
        int o = off[i] + bsum[i / SCAN_B];
        off[i] = o;
        cur[i] = o;
    }
}

// ---------------- fill target-sorted edge list: {src, norm} packed ----------------
__global__ void k_fill(const int* __restrict__ row, const int* __restrict__ col,
                       const float* __restrict__ ew, const float* __restrict__ dis,
                       int* __restrict__ cur, int2* __restrict__ es) {
    int e = blockIdx.x * blockDim.x + threadIdx.x;
    if (e < N_EDGES) {
        int r = row[e], c = col[e];
        float w = dis[r] * ew[e] * dis[c];
        int p = atomicAdd(&cur[c], 1);
        es[p] = make_int2(r, __float_as_int(w));
    }
}

// ---------------- layer 1 GEMM: h = x @ W1^T ----------------
// 8 threads/row, 4 consecutive output feats each. W1 (32KB) is L1-resident;
// x rows read once from HBM as 8-lane float4 broadcast groups.
__global__ __launch_bounds__(256) void k_gemm1(
        const float* __restrict__ x, const float* __restrict__ W1,
        float* __restrict__ h) {
    int t = blockIdx.x * blockDim.x + threadIdx.x;
    int rowi = t >> 3;
    if (rowi >= N_NODES) return;
    int og = t & 7;

    const float4* xr = (const float4*)(x + (size_t)rowi * FEAT);
    const float4* w0 = (const float4*)(W1 + (og * 4 + 0) * FEAT);
    const float4* w1 = (const float4*)(W1 + (og * 4 + 1) * FEAT);
    const float4* w2 = (const float4*)(W1 + (og * 4 + 2) * FEAT);
    const float4* w3 = (const float4*)(W1 + (og * 4 + 3) * FEAT);

    float a0 = 0.f, a1 = 0.f, a2 = 0.f, a3 = 0.f;
#pragma unroll 4
    for (int k = 0; k < FEAT / 4; ++k) {
        float4 xv = xr[k];
        float4 wv;
        wv = w0[k]; a0 += xv.x * wv.x + xv.y * wv.y + xv.z * wv.z + xv.w * wv.w;
        wv = w1[k]; a1 += xv.x * wv.x + xv.y * wv.y + xv.z * wv.z + xv.w * wv.w;
        wv = w2[k]; a2 += xv.x * wv.x + xv.y * wv.y + xv.z * wv.z + xv.w * wv.w;
        wv = w3[k]; a3 += xv.x * wv.x + xv.y * wv.y + xv.z * wv.z + xv.w * wv.w;
    }
    *(float4*)(h + (size_t)rowi * HIDDEN + og * 4) = make_float4(a0, a1, a2, a3);
}

// ---------------- layer 1 gather: out1[c] = sum_in h[src]*w + h[c]*d^2 + b1 ----
__global__ __launch_bounds__(256) void k_gather1(
        const int* __restrict__ off, const int* __restrict__ cur,
        const int2* __restrict__ es, const float* __restrict__ h,
        const float* __restrict__ dis, const float* __restrict__ b1,
        float* __restrict__ out1) {
    int t = blockIdx.x * blockDim.x + threadIdx.x;
    int node = t >> 3;
    if (node >= N_NODES) return;
    int og = t & 7;

    float d = dis[node];
    float d2 = d * d;
    float4 self = *(const float4*)(h + (size_t)node * HIDDEN + og * 4);
    float4 bv = *(const float4*)(b1 + og * 4);
    float4 acc = make_float4(self.x * d2 + bv.x, self.y * d2 + bv.y,
                             self.z * d2 + bv.z, self.w * d2 + bv.w);

    int j = off[node], end = cur[node];
    for (; j < end; ++j) {
        int2 e = es[j];
        float w = __int_as_float(e.y);
        float4 hv = *(const float4*)(h + (size_t)e.x * HIDDEN + og * 4);
        acc.x += hv.x * w; acc.y += hv.y * w; acc.z += hv.z * w; acc.w += hv.w * w;
    }
    *(float4*)(out1 + (size_t)node * HIDDEN + og * 4) = acc;
}

// ---------------- layer 2 GEMM: h2 = relu(out1) @ W2^T ----------------
__global__ void k_gemm2(const float* __restrict__ out1, const float* __restrict__ W2,
                        float* __restrict__ h2) {
    int t = blockIdx.x * blockDim.x + threadIdx.x;
    int i = t >> 4;
    if (i >= N_NODES) return;
    int f = t & 15;
    const float* r = out1 + (size_t)i * HIDDEN;
    const float* w = W2 + f * HIDDEN;
    float acc = 0.f;
#pragma unroll
    for (int k = 0; k < HIDDEN; ++k) acc += fmaxf(r[k], 0.f) * w[k];
    h2[(size_t)i * EMBED + f] = acc;
}

// ---------------- layer 2 gather: out[c] = sum_in h2[src]*w + h2[c]*d^2 + b2 ----
__global__ __launch_bounds__(256) void k_gather2(
        const int* __restrict__ off, const int* __restrict__ cur,
        const int2* __restrict__ es, const float* __restrict__ h2,
        const float* __restrict__ dis, const float* __restrict__ b2,
        float* __restrict__ out) {
    int t = blockIdx.x * blockDim.x + threadIdx.x;
    int node = t >> 2;
    if (node >= N_NODES) return;
    int og = t & 3;

    float d = dis[node];
    float d2 = d * d;
    float4 self = *(const float4*)(h2 + (size_t)node * EMBED + og * 4);
    float4 bv = *(const float4*)(b2 + og * 4);
    float4 acc = make_float4(self.x * d2 + bv.x, self.y * d2 + bv.y,
                             self.z * d2 + bv.z, self.w * d2 + bv.w);

    int j = off[node], end = cur[node];
    for (; j < end; ++j) {
        int2 e = es[j];
        float w = __int_as_float(e.y);
        float4 hv = *(const float4*)(h2 + (size_t)e.x * EMBED + og * 4);
        acc.x += hv.x * w; acc.y += hv.y * w; acc.z += hv.z * w; acc.w += hv.w * w;
    }
    *(float4*)(out + (size_t)node * EMBED + og * 4) = acc;
}

extern "C" void kernel_launch(void* const* d_in, const int* in_sizes, int n_in,
                              void* d_out, int out_size, void* d_ws, size_t ws_size,
                              hipStream_t stream) {
    const float* x  = (const float*)d_in[0];
    const int*   ei = (const int*)d_in[1];  // [2, E] int32
    const float* ew = (const float*)d_in[2];
    const float* W1 = (const float*)d_in[3];
    const float* b1 = (const float*)d_in[4];
    const float* W2 = (const float*)d_in[5];
    const float* b2 = (const float*)d_in[6];
    float* out = (float*)d_out;

    const int* row = ei;            // source
    const int* col = ei + N_EDGES;  // target

    // ws layout (4B elems): dis[N] cnt[N] off[N] cur[N] bsum[256] es[2E] h[32N] out1[32N]
    float* dis  = (float*)d_ws;
    int*   cnt  = (int*)(dis + N_NODES);
    int*   off  = cnt + N_NODES;
    int*   cur  = off + N_NODES;
    int*   bsum = cur + N_NODES;
    int2*  es   = (int2*)(bsum + 256);            // 8B-aligned (400256 elems * 4B)
    float* h    = (float*)(es + N_EDGES);         // 16B-aligned
    float* out1 = h + (size_t)N_NODES * HIDDEN;
    float* h2   = h;  // alias: h dead after k_gather1

    const int B = 256;
    const int gN = (N_NODES + B - 1) / B;
    const int gE = (N_EDGES + B - 1) / B;

    k_init<<<gN, B, 0, stream>>>(dis, cnt);
    k_edge_count<<<gE, B, 0, stream>>>(col, ew, cnt, dis);
    k_dis<<<gN, B, 0, stream>>>(dis);
    k_scan_block<<<NB, SCAN_B, 0, stream>>>(cnt, off, bsum);
    k_scan_bsum<<<1, 64, 0, stream>>>(bsum);
    k_scan_add<<<gN, B, 0, stream>>>(off, bsum, cur);
    k_fill<<<gE, B, 0, stream>>>(row, col, ew, dis, cur, es);
    k_gemm1<<<(N_NODES * 8 + B - 1) / B, B, 0, stream>>>(x, W1, h);
    k_gather1<<<(N_NODES * 8 + B - 1) / B, B, 0, stream>>>(off, cur, es, h, dis, b1, out1);
    k_gemm2<<<(N_NODES * 16 + B - 1) / B, B, 0, stream>>>(out1, W2, h2);
    k_gather2<<<(N_NODES * 4 + B - 1) / B, B, 0, stream>>>(off, cur, es, h2, dis, b2, out);
}

// Round 6
// 714.023 us; speedup vs baseline: 3.5633x; 1.4083x over previous
//
#include <hip/hip_runtime.h>
#include <hip/hip_bf16.h>

#define N_NODES 100000
#define N_EDGES 3200000
#define FEAT 256
#define HIDDEN 32
#define EMBED 16
#define SCAN_B 512
#define NB ((N_NODES + SCAN_B - 1) / SCAN_B)  // 196
#define TR 64        // rows per gemm1 block
#define PAD 4        // LDS row pad (floats): row stride 260*4=1040B -> 4-bank shift/row

// ---------------- init: deg=1 (self loop), cnt=0 ----------------
__global__ void k_init(float* __restrict__ deg, int* __restrict__ cnt) {
    int i = blockIdx.x * blockDim.x + threadIdx.x;
    if (i < N_NODES) { deg[i] = 1.0f; cnt[i] = 0; }
}

// ---------------- per-edge: count targets + weighted degree ----------------
__global__ void k_edge_count(const int* __restrict__ col, const float* __restrict__ ew,
                             int* __restrict__ cnt, float* __restrict__ deg) {
    int e = blockIdx.x * blockDim.x + threadIdx.x;
    if (e < N_EDGES) {
        int c = col[e];
        atomicAdd(&cnt[c], 1);
        unsafeAtomicAdd(&deg[c], ew[e]);
    }
}

__global__ void k_dis(float* __restrict__ deg) {
    int i = blockIdx.x * blockDim.x + threadIdx.x;
    if (i < N_NODES) {
        float d = deg[i];
        deg[i] = (d > 0.0f) ? rsqrtf(d) : 0.0f;  // in-place deg -> deg^{-1/2}
    }
}

// ---------------- exclusive scan of cnt -> off (3 kernels) ----------------
__global__ __launch_bounds__(SCAN_B) void k_scan_block(
        const int* __restrict__ cnt, int* __restrict__ off, int* __restrict__ bsum) {
    __shared__ int s[SCAN_B];
    int tid = threadIdx.x;
    int i = blockIdx.x * SCAN_B + tid;
    int v = (i < N_NODES) ? cnt[i] : 0;
    s[tid] = v;
    __syncthreads();
    for (int d = 1; d < SCAN_B; d <<= 1) {
        int t = (tid >= d) ? s[tid - d] : 0;
        __syncthreads();
        s[tid] += t;
        __syncthreads();
    }
    if (i < N_NODES) off[i] = s[tid] - v;  // exclusive within block
    if (tid == SCAN_B - 1) bsum[blockIdx.x] = s[tid];
}

__global__ void k_scan_bsum(int* __restrict__ bsum) {
    if (threadIdx.x == 0 && blockIdx.x == 0) {
        int run = 0;
        for (int b = 0; b < NB; ++b) { int t = bsum[b]; bsum[b] = run; run += t; }
    }
}

__global__ void k_scan_add(int* __restrict__ off, const int* __restrict__ bsum,
                           int* __restrict__ cur) {
    int i = blockIdx.x * blockDim.x + threadIdx.x;
    if (i < N_NODES) {
        int o = off[i] + bsum[i / SCAN_B];
        off[i] = o;
        cur[i] = o;
    }
}

// ---------------- fill target-sorted edge list: {src, norm} packed ----------------
__global__ void k_fill(const int* __restrict__ row, const int* __restrict__ col,
                       const float* __restrict__ ew, const float* __restrict__ dis,
                       int* __restrict__ cur, int2* __restrict__ es) {
    int e = blockIdx.x * blockDim.x + threadIdx.x;
    if (e < N_EDGES) {
        int r = row[e], c = col[e];
        float w = dis[r] * ew[e] * dis[c];
        int p = atomicAdd(&cur[c], 1);
        es[p] = make_int2(r, __float_as_int(w));
    }
}

// ---------------- layer 1 GEMM: h = x @ W1^T, LDS-tiled ----------------
// 64-row x tile + full W1 in LDS (both row-padded +4 floats => 4-bank shift/row,
// conflict-free ds_read_b128 for both operands). Thread = 2 rows x 4 cols
// (cols strided by 8). Per k-quad: 6 ds_read_b128 + 32 FMA.
__global__ __launch_bounds__(256) void k_gemm1(
        const float* __restrict__ x, const float* __restrict__ W1,
        float* __restrict__ h) {
    __shared__ float sx[TR][FEAT + PAD];      // 64*260*4 = 66560 B
    __shared__ float sw[HIDDEN][FEAT + PAD];  // 32*260*4 = 33280 B

    const int tid = threadIdx.x;
    const size_t base = (size_t)blockIdx.x * TR;
    const float4* x4 = (const float4*)x;
    const float4* w4 = (const float4*)W1;

    // stage W1: 32 rows x 64 float4; coalesced global, conflict-free LDS writes
    for (int i = tid; i < HIDDEN * (FEAT / 4); i += 256) {
        int f = i >> 6, kq = i & 63;
        *(float4*)&sw[f][kq * 4] = w4[f * 64 + kq];
    }
    // stage x tile: 64 rows x 64 float4 (zero-fill OOB rows of last block)
    for (int i = tid; i < TR * (FEAT / 4); i += 256) {
        int r = i >> 6, kq = i & 63;
        float4 v = make_float4(0.f, 0.f, 0.f, 0.f);
        if (base + r < N_NODES) v = x4[(base + r) * (FEAT / 4) + kq];
        *(float4*)&sx[r][kq * 4] = v;
    }
    __syncthreads();

    const int r0 = tid >> 3;   // 0..31; rows r0 and r0+32
    const int c0 = tid & 7;    // cols c0 + 8*j, j=0..3
    float acc[2][4] = {{0.f, 0.f, 0.f, 0.f}, {0.f, 0.f, 0.f, 0.f}};

#pragma unroll 4
    for (int kq = 0; kq < FEAT / 4; ++kq) {
        float4 xa = *(const float4*)&sx[r0][kq * 4];
        float4 xb = *(const float4*)&sx[r0 + 32][kq * 4];
#pragma unroll
        for (int j = 0; j < 4; ++j) {
            float4 wv = *(const float4*)&sw[c0 + 8 * j][kq * 4];
            acc[0][j] += xa.x * wv.x + xa.y * wv.y + xa.z * wv.z + xa.w * wv.w;
            acc[1][j] += xb.x * wv.x + xb.y * wv.y + xb.z * wv.z + xb.w * wv.w;
        }
    }

    size_t ra = base + r0, rb = base + r0 + 32;
    if (ra < N_NODES) {
#pragma unroll
        for (int j = 0; j < 4; ++j) h[ra * HIDDEN + c0 + 8 * j] = acc[0][j];
    }
    if (rb < N_NODES) {
#pragma unroll
        for (int j = 0; j < 4; ++j) h[rb * HIDDEN + c0 + 8 * j] = acc[1][j];
    }
}

// ---------------- layer 1 gather: out1[c] = sum_in h[src]*w + h[c]*d^2 + b1 ----
__global__ __launch_bounds__(256) void k_gather1(
        const int* __restrict__ off, const int* __restrict__ cur,
        const int2* __restrict__ es, const float* __restrict__ h,
        const float* __restrict__ dis, const float* __restrict__ b1,
        float* __restrict__ out1) {
    int t = blockIdx.x * blockDim.x + threadIdx.x;
    int node = t >> 3;
    if (node >= N_NODES) return;
    int og = t & 7;

    float d = dis[node];
    float d2 = d * d;
    float4 self = *(const float4*)(h + (size_t)node * HIDDEN + og * 4);
    float4 bv = *(const float4*)(b1 + og * 4);
    float4 acc = make_float4(self.x * d2 + bv.x, self.y * d2 + bv.y,
                             self.z * d2 + bv.z, self.w * d2 + bv.w);

    int j = off[node], end = cur[node];
    for (; j < end; ++j) {
        int2 e = es[j];
        float w = __int_as_float(e.y);
        float4 hv = *(const float4*)(h + (size_t)e.x * HIDDEN + og * 4);
        acc.x += hv.x * w; acc.y += hv.y * w; acc.z += hv.z * w; acc.w += hv.w * w;
    }
    *(float4*)(out1 + (size_t)node * HIDDEN + og * 4) = acc;
}

// ---------------- layer 2 GEMM: h2 = relu(out1) @ W2^T ----------------
__global__ void k_gemm2(const float* __restrict__ out1, const float* __restrict__ W2,
                        float* __restrict__ h2) {
    int t = blockIdx.x * blockDim.x + threadIdx.x;
    int i = t >> 4;
    if (i >= N_NODES) return;
    int f = t & 15;
    const float* r = out1 + (size_t)i * HIDDEN;
    const float* w = W2 + f * HIDDEN;
    float acc = 0.f;
#pragma unroll
    for (int k = 0; k < HIDDEN; ++k) acc += fmaxf(r[k], 0.f) * w[k];
    h2[(size_t)i * EMBED + f] = acc;
}

// ---------------- layer 2 gather: out[c] = sum_in h2[src]*w + h2[c]*d^2 + b2 ----
__global__ __launch_bounds__(256) void k_gather2(
        const int* __restrict__ off, const int* __restrict__ cur,
        const int2* __restrict__ es, const float* __restrict__ h2,
        const float* __restrict__ dis, const float* __restrict__ b2,
        float* __restrict__ out) {
    int t = blockIdx.x * blockDim.x + threadIdx.x;
    int node = t >> 2;
    if (node >= N_NODES) return;
    int og = t & 3;

    float d = dis[node];
    float d2 = d * d;
    float4 self = *(const float4*)(h2 + (size_t)node * EMBED + og * 4);
    float4 bv = *(const float4*)(b2 + og * 4);
    float4 acc = make_float4(self.x * d2 + bv.x, self.y * d2 + bv.y,
                             self.z * d2 + bv.z, self.w * d2 + bv.w);

    int j = off[node], end = cur[node];
    for (; j < end; ++j) {
        int2 e = es[j];
        float w = __int_as_float(e.y);
        float4 hv = *(const float4*)(h2 + (size_t)e.x * EMBED + og * 4);
        acc.x += hv.x * w; acc.y += hv.y * w; acc.z += hv.z * w; acc.w += hv.w * w;
    }
    *(float4*)(out + (size_t)node * EMBED + og * 4) = acc;
}

extern "C" void kernel_launch(void* const* d_in, const int* in_sizes, int n_in,
                              void* d_out, int out_size, void* d_ws, size_t ws_size,
                              hipStream_t stream) {
    const float* x  = (const float*)d_in[0];
    const int*   ei = (const int*)d_in[1];  // [2, E] int32
    const float* ew = (const float*)d_in[2];
    const float* W1 = (const float*)d_in[3];
    const float* b1 = (const float*)d_in[4];
    const float* W2 = (const float*)d_in[5];
    const float* b2 = (const float*)d_in[6];
    float* out = (float*)d_out;

    const int* row = ei;            // source
    const int* col = ei + N_EDGES;  // target

    // ws layout (4B elems): dis[N] cnt[N] off[N] cur[N] bsum[256] es[2E] h[32N] out1[32N]
    float* dis  = (float*)d_ws;
    int*   cnt  = (int*)(dis + N_NODES);
    int*   off  = cnt + N_NODES;
    int*   cur  = off + N_NODES;
    int*   bsum = cur + N_NODES;
    int2*  es   = (int2*)(bsum + 256);            // 8B-aligned
    float* h    = (float*)(es + N_EDGES);         // 16B-aligned
    float* out1 = h + (size_t)N_NODES * HIDDEN;
    float* h2   = h;  // alias: h dead after k_gather1

    const int B = 256;
    const int gN = (N_NODES + B - 1) / B;
    const int gE = (N_EDGES + B - 1) / B;

    k_init<<<gN, B, 0, stream>>>(dis, cnt);
    k_edge_count<<<gE, B, 0, stream>>>(col, ew, cnt, dis);
    k_dis<<<gN, B, 0, stream>>>(dis);
    k_scan_block<<<NB, SCAN_B, 0, stream>>>(cnt, off, bsum);
    k_scan_bsum<<<1, 64, 0, stream>>>(bsum);
    k_scan_add<<<gN, B, 0, stream>>>(off, bsum, cur);
    k_fill<<<gE, B, 0, stream>>>(row, col, ew, dis, cur, es);
    k_gemm1<<<(N_NODES + TR - 1) / TR, B, 0, stream>>>(x, W1, h);
    k_gather1<<<(N_NODES * 8 + B - 1) / B, B, 0, stream>>>(off, cur, es, h, dis, b1, out1);
    k_gemm2<<<(N_NODES * 16 + B - 1) / B, B, 0, stream>>>(out1, W2, h2);
    k_gather2<<<(N_NODES * 4 + B - 1) / B, B, 0, stream>>>(off, cur, es, h2, dis, b2, out);
}